// Round 9
// baseline (12994.154 us; speedup 1.0000x reference)
//
#include <hip/hip_runtime.h>
#include <cstdint>
#include <cstddef>

// Problem dims (fixed by reference)
#define B_    64
#define T_    4096
#define H_    128
#define C1_   64
#define NCLS_ 40

#define LOG2E_    1.4426950408889634f
#define TWOLOG2E_ 2.8853900817779268f

typedef _Float16 half2_t __attribute__((ext_vector_type(2)));

__device__ __forceinline__ float fdot2(half2_t a, half2_t b, float c){
#if defined(__has_builtin) && __has_builtin(__builtin_amdgcn_fdot2)
  return __builtin_amdgcn_fdot2(a, b, c, false);   // v_dot2_f32_f16, full-rate
#else
  return fmaf((float)a.x, (float)b.x, fmaf((float)a.y, (float)b.y, c));
#endif
}
__device__ __forceinline__ half2_t bc2(unsigned int u){ return __builtin_bit_cast(half2_t, u); }
__device__ __forceinline__ half2_t pack2(float a, float b){
  half2_t r; r.x = (_Float16)a; r.y = (_Float16)b; return r;   // RTNE
}
template<int CTRL>
__device__ __forceinline__ float qperm(float x){
  return __int_as_float(__builtin_amdgcn_update_dpp(0, __float_as_int(x), CTRL, 0xF, 0xF, true));
}

// ---------------- kernel 1: 3x3 second-moment stats of x over B*T ----------------
__global__ __launch_bounds__(256) void stats_kernel(const float* __restrict__ x,
                                                    float* __restrict__ stats){
  int t = blockIdx.x * 256 + threadIdx.x;
  const float4* xv = (const float4*)x + (size_t)t * 3;
  float4 a = xv[0], b = xv[1], c = xv[2];
  float x0[4] = {a.x, a.w, b.z, c.y};
  float x1[4] = {a.y, b.x, b.w, c.z};
  float x2[4] = {a.z, b.y, c.x, c.w};
  float s[9] = {0,0,0,0,0,0,0,0,0};
  #pragma unroll
  for (int r=0;r<4;++r){
    s[0]+=x0[r]; s[1]+=x1[r]; s[2]+=x2[r];
    s[3]+=x0[r]*x0[r]; s[4]+=x0[r]*x1[r]; s[5]+=x0[r]*x2[r];
    s[6]+=x1[r]*x1[r]; s[7]+=x1[r]*x2[r]; s[8]+=x2[r]*x2[r];
  }
  __shared__ float red[9][256];
  #pragma unroll
  for (int j=0;j<9;++j) red[j][threadIdx.x] = s[j];
  __syncthreads();
  if (threadIdx.x < 9){
    float sum = 0.f;
    for (int i=0;i<256;++i) sum += red[threadIdx.x][i];
    atomicAdd(&stats[threadIdx.x], sum);
  }
}

// Fold conv + BN(train stats) + gamma/beta into per-channel affine. conv_b cancels.
__device__ __forceinline__ void chan_affine(int c, const float* __restrict__ conv_w,
    const float* __restrict__ bn_g, const float* __restrict__ bn_b,
    const float* __restrict__ stats,
    float& A0, float& A1, float& A2, float& Bc){
  const float Ninv = 1.0f / (float)(B_*T_);
  float m0=stats[0]*Ninv, m1=stats[1]*Ninv, m2=stats[2]*Ninv;
  float c00=stats[3]*Ninv-m0*m0, c01=stats[4]*Ninv-m0*m1, c02=stats[5]*Ninv-m0*m2;
  float c11=stats[6]*Ninv-m1*m1, c12=stats[7]*Ninv-m1*m2, c22=stats[8]*Ninv-m2*m2;
  float w0=conv_w[c*3+0], w1=conv_w[c*3+1], w2=conv_w[c*3+2];
  float var = w0*(w0*c00 + 2.f*(w1*c01 + w2*c02)) + w1*(w1*c11 + 2.f*w2*c12) + w2*w2*c22;
  float sc = bn_g[c] * rsqrtf(var + 1e-5f);
  A0 = w0*sc; A1 = w1*sc; A2 = w2*sc;
  Bc = bn_b[c] - (w0*m0 + w1*m1 + w2*m2)*sc;
}

// ---------------- kernel 2 (Tier A): y = relu(affine(x)) as f16 [B][T][64] ----------------
__global__ __launch_bounds__(256) void y_kernel(const float* __restrict__ x,
    const float* __restrict__ conv_w, const float* __restrict__ bn_g,
    const float* __restrict__ bn_b, const float* __restrict__ stats,
    _Float16* __restrict__ yg){
  __shared__ float4 coef[C1_];
  int tid = threadIdx.x;
  if (tid < C1_){
    float A0,A1,A2,Bc; chan_affine(tid, conv_w, bn_g, bn_b, stats, A0,A1,A2,Bc);
    coef[tid] = make_float4(A0,A1,A2,Bc);
  }
  __syncthreads();
  size_t idx = (size_t)blockIdx.x * 256 + tid;      // (b*T + t)
  const float* xp = x + idx*3;
  float x0 = xp[0], x1 = xp[1], x2 = xp[2];
  unsigned int ob[32];
  #pragma unroll
  for (int c=0; c<C1_; c+=2){
    float4 c0 = coef[c], c1 = coef[c+1];
    float v0 = fmaxf(fmaf(c0.x,x0, fmaf(c0.y,x1, fmaf(c0.z,x2, c0.w))), 0.f);
    float v1 = fmaxf(fmaf(c1.x,x0, fmaf(c1.y,x1, fmaf(c1.z,x2, c1.w))), 0.f);
    ob[c>>1] = __builtin_bit_cast(unsigned int, pack2(v0, v1));
  }
  uint4* dst = (uint4*)(yg + idx*C1_);
  #pragma unroll
  for (int i=0;i<8;++i) dst[i] = ((uint4*)ob)[i];
}

// ---------------- kernel 3 (Tier A): staggered-group LSTM, flag-synced ----------------
// 64 blocks x 512 threads. Group gid=t>>8 handles steps of parity gid (waves 0-3 vs 4-7:
// one wave of each group per SIMD -> the other group's issue covers my stalls).
// Thread: k=(t&255)>>1, s=t&1 (64-wide h half / 32-wide y half). 4 gates x (64h+32y)
// = 192 dot2/step. h (f16) and scaled-c (f32) ping-pong via LDS parity buffers.
// Sync: per-wave LDS flags. Consumer issues flag-reads THEN h/c-reads (DS pipe is
// in-order per wave -> flag==t-1 proves h/c final at sample time), covers latency
// with y-dots, checks once after lgkmcnt(0); rare retry re-issues everything.
// Producer publishes flag after its writes drain. Overwrite of h(t-2) is gated
// transitively: other group's step-(t-1) flag implies its reads of h(t-2) are done.
__global__ __launch_bounds__(512,2) void lstm_flag_kernel(
    const _Float16* __restrict__ yg,
    const float* __restrict__ w_ih, const float* __restrict__ b_ih,
    const float* __restrict__ b_hh, const float* __restrict__ w_hh,
    const float* __restrict__ h0, const float* __restrict__ c0,
    const float* __restrict__ out_w, const float* __restrict__ out_b,
    float* __restrict__ out){
  int b = blockIdx.x, t = threadIdx.x;
  int gid = t >> 8;                      // 0: even steps, 1: odd steps
  int loc = t & 255;
  int k = loc >> 1, s = loc & 1;
  int wv = t >> 6;                       // wave id 0..7
  int ow = gid ? 0 : 4;                  // other group's wave base
  __shared__ __align__(16) _Float16 hbuf[2][H_];   // h(t) -> hbuf[(t+1)&1]
  __shared__ __align__(16) float    cbuf[2][H_];   // scaled c, same parity
  __shared__ int wfl[8];

  // weights as half2, prescaled by gate exp2-scale: sg = -log2e (I,F,O), +2log2e (G)
  half2_t wh[4][32];                     // h cols [s*64, s*64+64)
  half2_t wy[4][16];                     // y cols [s*32, s*32+32)
  float bias[4];
  #pragma unroll
  for (int g=0; g<4; ++g){
    float sg = (g==2) ? TWOLOG2E_ : -LOG2E_;
    const float4* p = (const float4*)(w_hh + (size_t)(g*H_ + k)*H_ + s*64);
    #pragma unroll
    for (int i=0;i<16;++i){
      float4 v = p[i];
      wh[g][2*i]   = pack2(sg*v.x, sg*v.y);
      wh[g][2*i+1] = pack2(sg*v.z, sg*v.w);
    }
    const float4* py = (const float4*)(w_ih + (size_t)(g*H_ + k)*C1_ + s*32);
    #pragma unroll
    for (int i=0;i<8;++i){
      float4 v = py[i];
      wy[g][2*i]   = pack2(sg*v.x, sg*v.y);
      wy[g][2*i+1] = pack2(sg*v.z, sg*v.w);
    }
    bias[g] = sg * (b_ih[g*H_+k] + b_hh[g*H_+k]);
  }

  if (t < 8) wfl[t] = -1;
  if (gid==0 && s==0){
    hbuf[0][k] = (_Float16)h0[(size_t)b*H_ + k];   // h(-1)
    cbuf[0][k] = TWOLOG2E_ * c0[(size_t)b*H_ + k]; // scaled c(-1)
  }
  __syncthreads();                                  // once, before the loop

  volatile int* vfl = wfl;
  const _Float16* ygb = yg + (size_t)b*T_*C1_ + s*32;
  // preload y(first step)
  uint4 yv0, yv1, yv2, yv3;
  { const _Float16* yp = ygb + (size_t)gid*C1_;
    yv0 = *(const uint4*)(yp); yv1 = *(const uint4*)(yp+8);
    yv2 = *(const uint4*)(yp+16); yv3 = *(const uint4*)(yp+24); }

  for (int st = gid; st < T_; st += 2){
    int p = st & 1;                      // read-buffer parity (holds h(st-1), c(st-1))
    float acc0=0.f, acc1=0.f, acc2=0.f, acc3=0.f;
    // ---- attempt-0: flag reads, then h/c reads (DS in-order), latency under y-dots ----
    int f0 = vfl[ow], f1 = vfl[ow+1], f2 = vfl[ow+2], f3 = vfl[ow+3];
    asm volatile("" ::: "memory");
    const _Float16* hb = &hbuf[p][s*64];
    uint4 hv0 = *(const uint4*)(hb);
    uint4 hv1 = *(const uint4*)(hb + 8);
    uint4 hv2 = *(const uint4*)(hb + 16);
    uint4 hv3 = *(const uint4*)(hb + 24);
    float cp  = cbuf[p][k];
    // y-dots (independent of h) cover the LDS read latency
    {
      half2_t y0_=bc2(yv0.x), y1_=bc2(yv0.y), y2_=bc2(yv0.z), y3_=bc2(yv0.w);
      half2_t y4_=bc2(yv1.x), y5_=bc2(yv1.y), y6_=bc2(yv1.z), y7_=bc2(yv1.w);
      half2_t y8_=bc2(yv2.x), y9_=bc2(yv2.y), yA_=bc2(yv2.z), yB_=bc2(yv2.w);
      half2_t yC_=bc2(yv3.x), yD_=bc2(yv3.y), yE_=bc2(yv3.z), yF_=bc2(yv3.w);
      half2_t ys[16] = {y0_,y1_,y2_,y3_,y4_,y5_,y6_,y7_,y8_,y9_,yA_,yB_,yC_,yD_,yE_,yF_};
      #pragma unroll
      for (int i=0;i<16;++i){
        acc0 = fdot2(wy[0][i], ys[i], acc0);
        acc1 = fdot2(wy[1][i], ys[i], acc1);
        acc2 = fdot2(wy[2][i], ys[i], acc2);
        acc3 = fdot2(wy[3][i], ys[i], acc3);
      }
    }
    uint4 hv4 = *(const uint4*)(hb + 32);
    uint4 hv5 = *(const uint4*)(hb + 40);
    uint4 hv6 = *(const uint4*)(hb + 48);
    uint4 hv7 = *(const uint4*)(hb + 56);
    // prefetch y(st+2) into the (now consumed) y regs — vmcnt domain, lands next iter
    { int tn = (st+2 < T_) ? st+2 : st;
      const _Float16* yp = ygb + (size_t)tn*C1_;
      yv0 = *(const uint4*)(yp); yv1 = *(const uint4*)(yp+8);
      yv2 = *(const uint4*)(yp+16); yv3 = *(const uint4*)(yp+24); }
    asm volatile("s_waitcnt lgkmcnt(0)" ::: "memory");
    int tm1 = st - 1;
    while (min(min(f0,f1),min(f2,f3)) < tm1){      // cold path: re-issue everything
      f0 = vfl[ow]; f1 = vfl[ow+1]; f2 = vfl[ow+2]; f3 = vfl[ow+3];
      asm volatile("" ::: "memory");
      hv0 = *(const uint4*)(hb);      hv1 = *(const uint4*)(hb + 8);
      hv2 = *(const uint4*)(hb + 16); hv3 = *(const uint4*)(hb + 24);
      hv4 = *(const uint4*)(hb + 32); hv5 = *(const uint4*)(hb + 40);
      hv6 = *(const uint4*)(hb + 48); hv7 = *(const uint4*)(hb + 56);
      cp  = cbuf[p][k];
      asm volatile("s_waitcnt lgkmcnt(0)" ::: "memory");
    }
    // ---- h-dots: 4 gates x 32 half2 ----
    uint4 hv[8] = {hv0,hv1,hv2,hv3,hv4,hv5,hv6,hv7};
    #pragma unroll
    for (int i=0;i<8;++i){
      half2_t a0 = bc2(hv[i].x), a1 = bc2(hv[i].y), a2 = bc2(hv[i].z), a3 = bc2(hv[i].w);
      acc0 = fdot2(wh[0][4*i+0], a0, acc0); acc0 = fdot2(wh[0][4*i+1], a1, acc0);
      acc0 = fdot2(wh[0][4*i+2], a2, acc0); acc0 = fdot2(wh[0][4*i+3], a3, acc0);
      acc1 = fdot2(wh[1][4*i+0], a0, acc1); acc1 = fdot2(wh[1][4*i+1], a1, acc1);
      acc1 = fdot2(wh[1][4*i+2], a2, acc1); acc1 = fdot2(wh[1][4*i+3], a3, acc1);
      acc2 = fdot2(wh[2][4*i+0], a0, acc2); acc2 = fdot2(wh[2][4*i+1], a1, acc2);
      acc2 = fdot2(wh[2][4*i+2], a2, acc2); acc2 = fdot2(wh[2][4*i+3], a3, acc2);
      acc3 = fdot2(wh[3][4*i+0], a0, acc3); acc3 = fdot2(wh[3][4*i+1], a1, acc3);
      acc3 = fdot2(wh[3][4*i+2], a2, acc3); acc3 = fdot2(wh[3][4*i+3], a3, acc3);
    }
    // pair butterfly (lane ^1): every lane gets all 4 full gate sums
    acc0 += qperm<0xB1>(acc0);
    acc1 += qperm<0xB1>(acc1);
    acc2 += qperm<0xB1>(acc2);
    acc3 += qperm<0xB1>(acc3);
    float g0 = acc0 + bias[0], g1 = acc1 + bias[1];
    float g2 = acc2 + bias[2], g3 = acc3 + bias[3];
    // lane-local activations (prescaled): sigmoid = rcp(1+exp2(v)); G = 1-2rcp(1+exp2(v))
    float Is = TWOLOG2E_ * __builtin_amdgcn_rcpf(1.f + __builtin_amdgcn_exp2f(g0));
    float F  = __builtin_amdgcn_rcpf(1.f + __builtin_amdgcn_exp2f(g1));
    float G  = fmaf(-2.f, __builtin_amdgcn_rcpf(1.f + __builtin_amdgcn_exp2f(g2)), 1.f);
    float O  = __builtin_amdgcn_rcpf(1.f + __builtin_amdgcn_exp2f(g3));
    float cs = fmaf(F, cp, Is*G);                  // scaled c(st)
    float th = fmaf(-2.f, __builtin_amdgcn_rcpf(1.f + __builtin_amdgcn_exp2f(cs)), 1.f);
    float h  = th * O;
    if (s == 0){
      hbuf[1-p][k] = (_Float16)h;
      cbuf[1-p][k] = cs;
    }
    asm volatile("s_waitcnt lgkmcnt(0)" ::: "memory");   // drain writes before publish
    if ((t & 63) == 0) vfl[wv] = st;
  }
  __syncthreads();
  // classifier epilogue: h(4095) -> hbuf[0]
  if (t < NCLS_){
    float sacc = out_b[t];
    #pragma unroll 8
    for (int kk=0; kk<H_; ++kk)
      sacc = fmaf(out_w[t*H_ + kk], (float)hbuf[0][kk], sacc);
    out[(size_t)b*NCLS_ + t] = sacc;
  }
}

// ---------------- Tier B fallback: R5 barrier kernel, in-kernel y (FUSED) ----------------
__global__ __launch_bounds__(512,2) void lstm_fallback_kernel(
    const float* __restrict__ x,
    const float* __restrict__ conv_w, const float* __restrict__ bn_g,
    const float* __restrict__ bn_b, const float* __restrict__ stats,
    const float* __restrict__ w_ih, const float* __restrict__ b_ih,
    const float* __restrict__ b_hh, const float* __restrict__ w_hh,
    const float* __restrict__ h0, const float* __restrict__ c0,
    const float* __restrict__ out_w, const float* __restrict__ out_b,
    float* __restrict__ out){
  int b = blockIdx.x, t = threadIdx.x;
  int k = t >> 2, w = t & 3;
  __shared__ __align__(16) _Float16 hbuf[2][H_];
  __shared__ __align__(16) _Float16 ybuf[4][C1_];
  half2_t wh[4][16];
  half2_t wy[4][8];
  #pragma unroll
  for (int g=0; g<4; ++g){
    float sg = (g==2) ? TWOLOG2E_ : -LOG2E_;
    const float4* p = (const float4*)(w_hh + (size_t)(g*H_ + k)*H_ + w*32);
    #pragma unroll
    for (int i=0;i<8;++i){
      float4 v = p[i];
      wh[g][2*i]   = pack2(sg*v.x, sg*v.y);
      wh[g][2*i+1] = pack2(sg*v.z, sg*v.w);
    }
    const float4* py = (const float4*)(w_ih + (size_t)(g*H_ + k)*C1_ + w*16);
    #pragma unroll
    for (int i=0;i<4;++i){
      float4 v = py[i];
      wy[g][2*i]   = pack2(sg*v.x, sg*v.y);
      wy[g][2*i+1] = pack2(sg*v.z, sg*v.w);
    }
  }
  float biasSel;
  { float sg = (w==2) ? TWOLOG2E_ : -LOG2E_;
    biasSel = sg * (b_ih[w*H_+k] + b_hh[w*H_+k]); }
  float Aa = (w==2) ?  1.f : 0.f;
  float Bb = (w==0) ? TWOLOG2E_ : ((w==2) ? -2.f : 1.f);
  bool o1 = (w & 1) != 0;
  bool o2 = (w & 2) != 0;
  float cs = TWOLOG2E_ * c0[(size_t)b*H_ + k];
  if (w == 0) hbuf[0][k] = (_Float16)h0[(size_t)b*H_ + k];
  int yc = t >> 3; bool prod = ((t & 7) == 0);
  float ya0=0, ya1=0, ya2=0, ya3=0;
  float xs0=0, xs1=0, xs2=0, xn0=0, xn1=0, xn2=0;
  const float* xb = x + (size_t)b*T_*3;
  chan_affine(yc, conv_w, bn_g, bn_b, stats, ya0, ya1, ya2, ya3);
  if (prod){
    float v0 = fmaf(ya0, xb[0], fmaf(ya1, xb[1], fmaf(ya2, xb[2], ya3)));
    float v1 = fmaf(ya0, xb[3], fmaf(ya1, xb[4], fmaf(ya2, xb[5], ya3)));
    ybuf[0][yc] = (_Float16)fmaxf(v0, 0.f);
    ybuf[1][yc] = (_Float16)fmaxf(v1, 0.f);
  }
  xs0 = xb[6];  xs1 = xb[7];  xs2 = xb[8];
  xn0 = xb[9];  xn1 = xb[10]; xn2 = xb[11];
  __syncthreads();
  #pragma unroll 2
  for (int step=0; step<T_; ++step){
    int p = step & 1;
    float acc[4] = {0.f,0.f,0.f,0.f};
    const _Float16* yb2 = &ybuf[step & 3][w*16];
    uint4 yv0 = *(const uint4*)(yb2);
    uint4 yv1 = *(const uint4*)(yb2 + 8);
    half2_t y0_ = bc2(yv0.x), y1_ = bc2(yv0.y), y2_ = bc2(yv0.z), y3_ = bc2(yv0.w);
    half2_t y4_ = bc2(yv1.x), y5_ = bc2(yv1.y), y6_ = bc2(yv1.z), y7_ = bc2(yv1.w);
    #pragma unroll
    for (int g=0; g<4; ++g){
      acc[g] = fdot2(wy[g][0], y0_, acc[g]);
      acc[g] = fdot2(wy[g][1], y1_, acc[g]);
      acc[g] = fdot2(wy[g][2], y2_, acc[g]);
      acc[g] = fdot2(wy[g][3], y3_, acc[g]);
      acc[g] = fdot2(wy[g][4], y4_, acc[g]);
      acc[g] = fdot2(wy[g][5], y5_, acc[g]);
      acc[g] = fdot2(wy[g][6], y6_, acc[g]);
      acc[g] = fdot2(wy[g][7], y7_, acc[g]);
    }
    float yn = fmaf(ya0, xs0, fmaf(ya1, xs1, fmaf(ya2, xs2, ya3)));
    if (prod) ybuf[(step+2) & 3][yc] = (_Float16)fmaxf(yn, 0.f);
    xs0=xn0; xs1=xn1; xs2=xn2;
    { int t4 = (step+4 < T_) ? step+4 : T_-1;
      const float* xp = xb + 3*t4; xn0=xp[0]; xn1=xp[1]; xn2=xp[2]; }
    asm volatile("s_waitcnt lgkmcnt(0)" ::: "memory");
    __builtin_amdgcn_s_barrier();
    asm volatile("" ::: "memory");
    const _Float16* hb = &hbuf[p][w*32];
    #pragma unroll
    for (int i=0;i<4;++i){
      uint4 hv = *(const uint4*)(hb + 8*i);
      half2_t h0_ = bc2(hv.x), h1_ = bc2(hv.y), h2_ = bc2(hv.z), h3_ = bc2(hv.w);
      #pragma unroll
      for (int g=0; g<4; ++g){
        acc[g] = fdot2(wh[g][4*i+0], h0_, acc[g]);
        acc[g] = fdot2(wh[g][4*i+1], h1_, acc[g]);
        acc[g] = fdot2(wh[g][4*i+2], h2_, acc[g]);
        acc[g] = fdot2(wh[g][4*i+3], h3_, acc[g]);
      }
    }
    float b01, b23;
    { float s0 = o1 ? acc[0] : acc[1];  float k0 = o1 ? acc[1] : acc[0];
      float s1 = o1 ? acc[2] : acc[3];  float k1 = o1 ? acc[3] : acc[2];
      b01 = k0 + qperm<0xB1>(s0);
      b23 = k1 + qperm<0xB1>(s1); }
    float accv;
    { float s = o2 ? b01 : b23;  float kk = o2 ? b23 : b01;
      accv = kk + qperm<0x4E>(s); }
    float v = accv + biasSel;
    float e = __builtin_amdgcn_exp2f(v);
    float act = fmaf(Bb, __builtin_amdgcn_rcpf(1.f + e), Aa);
    float dA = qperm<0x1B>(act);
    float bp = qperm<0x4E>(act);
    float pp = act * (o1 ? cs : bp);
    float cps = pp + qperm<0xB1>(pp);
    cps = qperm<0x00>(cps);
    cs = cps;
    float th = fmaf(-2.f, __builtin_amdgcn_rcpf(1.f + __builtin_amdgcn_exp2f(cps)), 1.f);
    float h = th * dA;
    if (w == 0) hbuf[1-p][k] = (_Float16)h;
  }
  __syncthreads();
  if (t < NCLS_){
    float s = out_b[t];
    #pragma unroll 8
    for (int kk=0; kk<H_; ++kk)
      s = fmaf(out_w[t*H_ + kk], (float)hbuf[0][kk], s);
    out[(size_t)b*NCLS_ + t] = s;
  }
}

extern "C" void kernel_launch(void* const* d_in, const int* in_sizes, int n_in,
                              void* d_out, int out_size, void* d_ws, size_t ws_size,
                              hipStream_t stream){
  const float* x      = (const float*)d_in[0];
  const float* conv_w = (const float*)d_in[1];
  // d_in[2] = conv_b: cancels exactly inside BN(train stats) — unused
  const float* bn_g   = (const float*)d_in[3];
  const float* bn_b   = (const float*)d_in[4];
  const float* w_ih   = (const float*)d_in[5];
  const float* b_ih   = (const float*)d_in[6];
  const float* w_hh   = (const float*)d_in[7];
  const float* b_hh   = (const float*)d_in[8];
  const float* out_w  = (const float*)d_in[9];
  const float* out_b  = (const float*)d_in[10];
  const float* h0     = (const float*)d_in[11];
  const float* c0     = (const float*)d_in[12];
  float* out      = (float*)d_out;
  float* stats    = (float*)d_ws;
  _Float16* yg    = (_Float16*)((char*)d_ws + 4096);
  const size_t needA = 4096 + (size_t)B_*T_*C1_*sizeof(_Float16);   // ~33.6 MB

  hipMemsetAsync(d_ws, 0, 64, stream);
  stats_kernel<<<256, 256, 0, stream>>>(x, stats);
  if (ws_size >= needA){
    y_kernel<<<(B_*T_)/256, 256, 0, stream>>>(x, conv_w, bn_g, bn_b, stats, yg);
    lstm_flag_kernel<<<B_, 512, 0, stream>>>(yg, w_ih, b_ih, b_hh, w_hh,
                                             h0, c0, out_w, out_b, out);
  } else {
    lstm_fallback_kernel<<<B_, 512, 0, stream>>>(x, conv_w, bn_g, bn_b, stats,
                                                 w_ih, b_ih, b_hh, w_hh, h0, c0,
                                                 out_w, out_b, out);
  }
}

// Round 10
// 2379.609 us; speedup vs baseline: 5.4606x; 5.4606x over previous
//
#include <hip/hip_runtime.h>
#include <cstdint>
#include <cstddef>

// Problem dims (fixed by reference)
#define B_    64
#define T_    4096
#define H_    128
#define C1_   64
#define NCLS_ 40

#define LOG2E_    1.4426950408889634f
#define TWOLOG2E_ 2.8853900817779268f

typedef _Float16 half2_t __attribute__((ext_vector_type(2)));

__device__ __forceinline__ float fdot2(half2_t a, half2_t b, float c){
#if defined(__has_builtin) && __has_builtin(__builtin_amdgcn_fdot2)
  return __builtin_amdgcn_fdot2(a, b, c, false);   // v_dot2_f32_f16, full-rate
#else
  return fmaf((float)a.x, (float)b.x, fmaf((float)a.y, (float)b.y, c));
#endif
}
__device__ __forceinline__ half2_t bc2(unsigned int u){ return __builtin_bit_cast(half2_t, u); }
__device__ __forceinline__ half2_t pack2(float a, float b){
  half2_t r; r.x = (_Float16)a; r.y = (_Float16)b; return r;   // RTNE
}
template<int CTRL>
__device__ __forceinline__ float qperm(float x){
  return __int_as_float(__builtin_amdgcn_update_dpp(0, __float_as_int(x), CTRL, 0xF, 0xF, true));
}

// ---------------- kernel 1: 3x3 second-moment stats of x over B*T ----------------
__global__ __launch_bounds__(256) void stats_kernel(const float* __restrict__ x,
                                                    float* __restrict__ stats){
  int t = blockIdx.x * 256 + threadIdx.x;
  const float4* xv = (const float4*)x + (size_t)t * 3;
  float4 a = xv[0], b = xv[1], c = xv[2];
  float x0[4] = {a.x, a.w, b.z, c.y};
  float x1[4] = {a.y, b.x, b.w, c.z};
  float x2[4] = {a.z, b.y, c.x, c.w};
  float s[9] = {0,0,0,0,0,0,0,0,0};
  #pragma unroll
  for (int r=0;r<4;++r){
    s[0]+=x0[r]; s[1]+=x1[r]; s[2]+=x2[r];
    s[3]+=x0[r]*x0[r]; s[4]+=x0[r]*x1[r]; s[5]+=x0[r]*x2[r];
    s[6]+=x1[r]*x1[r]; s[7]+=x1[r]*x2[r]; s[8]+=x2[r]*x2[r];
  }
  __shared__ float red[9][256];
  #pragma unroll
  for (int j=0;j<9;++j) red[j][threadIdx.x] = s[j];
  __syncthreads();
  if (threadIdx.x < 9){
    float sum = 0.f;
    for (int i=0;i<256;++i) sum += red[threadIdx.x][i];
    atomicAdd(&stats[threadIdx.x], sum);
  }
}

// Fold conv + BN(train stats) + gamma/beta into per-channel affine. conv_b cancels.
__device__ __forceinline__ void chan_affine(int c, const float* __restrict__ conv_w,
    const float* __restrict__ bn_g, const float* __restrict__ bn_b,
    const float* __restrict__ stats,
    float& A0, float& A1, float& A2, float& Bc){
  const float Ninv = 1.0f / (float)(B_*T_);
  float m0=stats[0]*Ninv, m1=stats[1]*Ninv, m2=stats[2]*Ninv;
  float c00=stats[3]*Ninv-m0*m0, c01=stats[4]*Ninv-m0*m1, c02=stats[5]*Ninv-m0*m2;
  float c11=stats[6]*Ninv-m1*m1, c12=stats[7]*Ninv-m1*m2, c22=stats[8]*Ninv-m2*m2;
  float w0=conv_w[c*3+0], w1=conv_w[c*3+1], w2=conv_w[c*3+2];
  float var = w0*(w0*c00 + 2.f*(w1*c01 + w2*c02)) + w1*(w1*c11 + 2.f*w2*c12) + w2*w2*c22;
  float sc = bn_g[c] * rsqrtf(var + 1e-5f);
  A0 = w0*sc; A1 = w1*sc; A2 = w2*sc;
  Bc = bn_b[c] - (w0*m0 + w1*m1 + w2*m2)*sc;
}

// ---------------- kernel 2 (Tier A): y = relu(affine(x)) as f16 [B][T+2][64] ----------------
// (T+2 rows per batch: rows T, T+1 are junk pads so the LSTM prefetch needs no clamp)
__global__ __launch_bounds__(256) void y_kernel(const float* __restrict__ x,
    const float* __restrict__ conv_w, const float* __restrict__ bn_g,
    const float* __restrict__ bn_b, const float* __restrict__ stats,
    _Float16* __restrict__ yg){
  __shared__ float4 coef[C1_];
  int tid = threadIdx.x;
  if (tid < C1_){
    float A0,A1,A2,Bc; chan_affine(tid, conv_w, bn_g, bn_b, stats, A0,A1,A2,Bc);
    coef[tid] = make_float4(A0,A1,A2,Bc);
  }
  __syncthreads();
  size_t idx = (size_t)blockIdx.x * 256 + tid;      // b*T + t
  int b = (int)(idx >> 12), t = (int)(idx & (T_-1));
  const float* xp = x + idx*3;
  float x0 = xp[0], x1 = xp[1], x2 = xp[2];
  unsigned int ob[32];
  #pragma unroll
  for (int c=0; c<C1_; c+=2){
    float4 c0 = coef[c], c1 = coef[c+1];
    float v0 = fmaxf(fmaf(c0.x,x0, fmaf(c0.y,x1, fmaf(c0.z,x2, c0.w))), 0.f);
    float v1 = fmaxf(fmaf(c1.x,x0, fmaf(c1.y,x1, fmaf(c1.z,x2, c1.w))), 0.f);
    ob[c>>1] = __builtin_bit_cast(unsigned int, pack2(v0, v1));
  }
  uint4* dst = (uint4*)(yg + ((size_t)b*(T_+2) + t)*C1_);
  #pragma unroll
  for (int i=0;i<8;++i) dst[i] = ((uint4*)ob)[i];
}

// ---------------- kernel 3: persistent per-batch LSTM (R5 structure) ----------------
// 64 blocks x 512 threads (8 waves, 2/SIMD — measured optimum of the barrier family:
// 4w=1578, 8w=1389, 16w=1688 cyc/step). thread t: k=t>>2, w=t&3 (32-wide h window /
// 16-wide y window). Pre-barrier: y-dots (y known a step early) + depth-2 y prefetch
// (ring-4 regs; covers HBM-latency spikes on L2-missed y rows). Raw s_barrier +
// lgkmcnt(0) so vmcnt prefetch stays in flight. Gate exp2-scales folded into W/bias;
// c carried scaled by 2log2e.
template<bool YG>
__global__ __launch_bounds__(512,2) void lstm_kernel(
    const _Float16* __restrict__ yg, const float* __restrict__ x,
    const float* __restrict__ conv_w, const float* __restrict__ bn_g,
    const float* __restrict__ bn_b, const float* __restrict__ stats,
    const float* __restrict__ w_ih, const float* __restrict__ b_ih,
    const float* __restrict__ b_hh, const float* __restrict__ w_hh,
    const float* __restrict__ h0, const float* __restrict__ c0,
    const float* __restrict__ out_w, const float* __restrict__ out_b,
    float* __restrict__ out){
  int b = blockIdx.x, t = threadIdx.x;
  int k = t >> 2, w = t & 3;
  __shared__ __align__(16) _Float16 hbuf[2][H_];
  __shared__ __align__(16) _Float16 ybuf[4][C1_];   // Tier B mod-4 ring

  // weights prescaled by gate exp2-scale: sg = -log2e (I,F,O), +2log2e (G)
  half2_t wh[4][16];
  half2_t wy[4][8];
  #pragma unroll
  for (int g=0; g<4; ++g){
    float sg = (g==2) ? TWOLOG2E_ : -LOG2E_;
    const float4* p = (const float4*)(w_hh + (size_t)(g*H_ + k)*H_ + w*32);
    #pragma unroll
    for (int i=0;i<8;++i){
      float4 v = p[i];
      wh[g][2*i]   = pack2(sg*v.x, sg*v.y);
      wh[g][2*i+1] = pack2(sg*v.z, sg*v.w);
    }
    const float4* py = (const float4*)(w_ih + (size_t)(g*H_ + k)*C1_ + w*16);
    #pragma unroll
    for (int i=0;i<4;++i){
      float4 v = py[i];
      wy[g][2*i]   = pack2(sg*v.x, sg*v.y);
      wy[g][2*i+1] = pack2(sg*v.z, sg*v.w);
    }
  }
  float biasSel;
  { float sg = (w==2) ? TWOLOG2E_ : -LOG2E_;
    biasSel = sg * (b_ih[w*H_+k] + b_hh[w*H_+k]); }
  float Aa = (w==2) ?  1.f : 0.f;
  float Bb = (w==0) ? TWOLOG2E_ : ((w==2) ? -2.f : 1.f);
  bool o1 = (w & 1) != 0;
  bool o2 = (w & 2) != 0;

  float cs = TWOLOG2E_ * c0[(size_t)b*H_ + k];      // scaled cell state
  if (w == 0) hbuf[0][k] = (_Float16)h0[(size_t)b*H_ + k];

  // ---- Tier B (in-kernel y) setup ----
  int yc = t >> 3; bool prod = ((t & 7) == 0);
  float ya0=0, ya1=0, ya2=0, ya3=0;
  float xs0=0, xs1=0, xs2=0, xn0=0, xn1=0, xn2=0;
  const float* xb = x + (size_t)b*T_*3;
  if constexpr (!YG){
    chan_affine(yc, conv_w, bn_g, bn_b, stats, ya0, ya1, ya2, ya3);
    if (prod){
      float v0 = fmaf(ya0, xb[0], fmaf(ya1, xb[1], fmaf(ya2, xb[2], ya3)));
      float v1 = fmaf(ya0, xb[3], fmaf(ya1, xb[4], fmaf(ya2, xb[5], ya3)));
      ybuf[0][yc] = (_Float16)fmaxf(v0, 0.f);
      ybuf[1][yc] = (_Float16)fmaxf(v1, 0.f);
    }
    xs0 = xb[6];  xs1 = xb[7];  xs2 = xb[8];        // x[2]
    xn0 = xb[9];  xn1 = xb[10]; xn2 = xb[11];       // x[3]
  }
  // ---- Tier A y preload: depth-2 prefetch, ring-4 register buffers ----
  const _Float16* ygb = nullptr;
  uint4 ypf[4][2];
  if constexpr (YG){
    ygb = yg + (size_t)b*(T_+2)*C1_ + w*16;
    ypf[0][0] = *(const uint4*)(ygb);           ypf[0][1] = *(const uint4*)(ygb + 8);
    ypf[1][0] = *(const uint4*)(ygb + C1_);     ypf[1][1] = *(const uint4*)(ygb + C1_ + 8);
  }
  __syncthreads();

  #pragma unroll 4
  for (int step=0; step<T_; ++step){
    int p  = step & 1;                              // const-folded per unrolled copy
    int r4 = step & 3;
    float acc[4] = {0.f,0.f,0.f,0.f};
    // ===== pre-barrier: prefetch y(step+2) first (max in-flight window), then y-dots =====
    if constexpr (YG){
      const _Float16* ypd = ygb + (size_t)(step+2)*C1_;    // rows T,T+1 are pads — no clamp
      ypf[(r4+2)&3][0] = *(const uint4*)(ypd);             // vmcnt domain; used 2 iters later
      ypf[(r4+2)&3][1] = *(const uint4*)(ypd + 8);
      uint4 yv0 = ypf[r4][0], yv1 = ypf[r4][1];
      half2_t y0_ = bc2(yv0.x), y1_ = bc2(yv0.y), y2_ = bc2(yv0.z), y3_ = bc2(yv0.w);
      half2_t y4_ = bc2(yv1.x), y5_ = bc2(yv1.y), y6_ = bc2(yv1.z), y7_ = bc2(yv1.w);
      #pragma unroll
      for (int g=0; g<4; ++g){
        acc[g] = fdot2(wy[g][0], y0_, acc[g]);
        acc[g] = fdot2(wy[g][1], y1_, acc[g]);
        acc[g] = fdot2(wy[g][2], y2_, acc[g]);
        acc[g] = fdot2(wy[g][3], y3_, acc[g]);
        acc[g] = fdot2(wy[g][4], y4_, acc[g]);
        acc[g] = fdot2(wy[g][5], y5_, acc[g]);
        acc[g] = fdot2(wy[g][6], y6_, acc[g]);
        acc[g] = fdot2(wy[g][7], y7_, acc[g]);
      }
    } else {
      const _Float16* yb2 = &ybuf[r4][w*16];        // written >=2 barriers ago
      uint4 yv0 = *(const uint4*)(yb2);
      uint4 yv1 = *(const uint4*)(yb2 + 8);
      half2_t y0_ = bc2(yv0.x), y1_ = bc2(yv0.y), y2_ = bc2(yv0.z), y3_ = bc2(yv0.w);
      half2_t y4_ = bc2(yv1.x), y5_ = bc2(yv1.y), y6_ = bc2(yv1.z), y7_ = bc2(yv1.w);
      #pragma unroll
      for (int g=0; g<4; ++g){
        acc[g] = fdot2(wy[g][0], y0_, acc[g]);
        acc[g] = fdot2(wy[g][1], y1_, acc[g]);
        acc[g] = fdot2(wy[g][2], y2_, acc[g]);
        acc[g] = fdot2(wy[g][3], y3_, acc[g]);
        acc[g] = fdot2(wy[g][4], y4_, acc[g]);
        acc[g] = fdot2(wy[g][5], y5_, acc[g]);
        acc[g] = fdot2(wy[g][6], y6_, acc[g]);
        acc[g] = fdot2(wy[g][7], y7_, acc[g]);
      }
      float yn = fmaf(ya0, xs0, fmaf(ya1, xs1, fmaf(ya2, xs2, ya3)));
      if (prod) ybuf[(step+2) & 3][yc] = (_Float16)fmaxf(yn, 0.f);   // y[step+2]
      xs0=xn0; xs1=xn1; xs2=xn2;
      { int t4 = (step+4 < T_) ? step+4 : T_-1;
        const float* xp = xb + 3*t4; xn0=xp[0]; xn1=xp[1]; xn2=xp[2]; }
    }
    // ===== barrier (LDS-only drain; vmcnt loads stay in flight) =====
    asm volatile("s_waitcnt lgkmcnt(0)" ::: "memory");
    __builtin_amdgcn_s_barrier();
    asm volatile("" ::: "memory");
    // ===== post-barrier: h-dots over [w*32, w*32+32) =====
    const _Float16* hb = &hbuf[p][w*32];
    #pragma unroll
    for (int i=0;i<4;++i){
      uint4 hv = *(const uint4*)(hb + 8*i);
      half2_t h0_ = bc2(hv.x), h1_ = bc2(hv.y), h2_ = bc2(hv.z), h3_ = bc2(hv.w);
      #pragma unroll
      for (int g=0; g<4; ++g){
        acc[g] = fdot2(wh[g][4*i+0], h0_, acc[g]);
        acc[g] = fdot2(wh[g][4*i+1], h1_, acc[g]);
        acc[g] = fdot2(wh[g][4*i+2], h2_, acc[g]);
        acc[g] = fdot2(wh[g][4*i+3], h3_, acc[g]);
      }
    }
    // reduce-scatter over quad: lane w ends with gate w's total
    float b01, b23;
    { float s0 = o1 ? acc[0] : acc[1];  float k0 = o1 ? acc[1] : acc[0];
      float s1 = o1 ? acc[2] : acc[3];  float k1 = o1 ? acc[3] : acc[2];
      b01 = k0 + qperm<0xB1>(s0);
      b23 = k1 + qperm<0xB1>(s1); }
    float accv;
    { float s = o2 ? b01 : b23;  float kk = o2 ? b23 : b01;
      accv = kk + qperm<0x4E>(s); }
    // activation (prescaled): act = Aa + Bb*rcp(1+exp2(v))
    float v = accv + biasSel;
    float e = __builtin_amdgcn_exp2f(v);
    float act = fmaf(Bb, __builtin_amdgcn_rcpf(1.f + e), Aa);
    // recombine: cs' = I_s*G + F*cs (lanes 0,1); h = tanh(c')*O
    float dA = qperm<0x1B>(act);                    // lane0 <- O
    float bp = qperm<0x4E>(act);                    // lane0 <- G
    float pp = act * (o1 ? cs : bp);                // lane0: I_s*G ; lane1: F*cs
    float cps = pp + qperm<0xB1>(pp);               // lanes 0,1: scaled c'
    cps = qperm<0x00>(cps);                         // broadcast to quad
    cs = cps;
    float th = fmaf(-2.f, __builtin_amdgcn_rcpf(1.f + __builtin_amdgcn_exp2f(cps)), 1.f);
    float h = th * dA;
    if (w == 0) hbuf[1-p][k] = (_Float16)h;
  }
  __syncthreads();
  // classifier epilogue on final h (T even -> buffer 0)
  if (t < NCLS_){
    float s = out_b[t];
    #pragma unroll 8
    for (int kk=0; kk<H_; ++kk)
      s = fmaf(out_w[t*H_ + kk], (float)hbuf[0][kk], s);
    out[(size_t)b*NCLS_ + t] = s;
  }
}

extern "C" void kernel_launch(void* const* d_in, const int* in_sizes, int n_in,
                              void* d_out, int out_size, void* d_ws, size_t ws_size,
                              hipStream_t stream){
  const float* x      = (const float*)d_in[0];
  const float* conv_w = (const float*)d_in[1];
  // d_in[2] = conv_b: cancels exactly inside BN(train stats) — unused
  const float* bn_g   = (const float*)d_in[3];
  const float* bn_b   = (const float*)d_in[4];
  const float* w_ih   = (const float*)d_in[5];
  const float* b_ih   = (const float*)d_in[6];
  const float* w_hh   = (const float*)d_in[7];
  const float* b_hh   = (const float*)d_in[8];
  const float* out_w  = (const float*)d_in[9];
  const float* out_b  = (const float*)d_in[10];
  const float* h0     = (const float*)d_in[11];
  const float* c0     = (const float*)d_in[12];
  float* out      = (float*)d_out;
  float* stats    = (float*)d_ws;
  _Float16* yg    = (_Float16*)((char*)d_ws + 4096);
  const size_t needA = 4096 + (size_t)B_*(T_+2)*C1_*sizeof(_Float16);   // ~33.6 MB

  hipMemsetAsync(d_ws, 0, 64, stream);
  stats_kernel<<<256, 256, 0, stream>>>(x, stats);
  if (ws_size >= needA){
    y_kernel<<<(B_*T_)/256, 256, 0, stream>>>(x, conv_w, bn_g, bn_b, stats, yg);
    lstm_kernel<true><<<B_, 512, 0, stream>>>(yg, x, conv_w, bn_g, bn_b, stats,
                                              w_ih, b_ih, b_hh, w_hh, h0, c0, out_w, out_b, out);
  } else {
    lstm_kernel<false><<<B_, 512, 0, stream>>>(yg, x, conv_w, bn_g, bn_b, stats,
                                               w_ih, b_ih, b_hh, w_hh, h0, c0, out_w, out_b, out);
  }
}